// Round 7
// baseline (493.032 us; speedup 1.0000x reference)
//
#include <hip/hip_runtime.h>

#define NEG_SLOPE 0.2f

typedef short bf16x8 __attribute__((ext_vector_type(8)));
typedef float f32x4 __attribute__((ext_vector_type(4)));

__device__ __forceinline__ float leaky1(float e) { return e > 0.f ? e : NEG_SLOPE * e; }

__device__ __forceinline__ unsigned short f2bf(float f) {
    unsigned u = __float_as_uint(f);
    u += 0x7fffu + ((u >> 16) & 1u);
    return (unsigned short)(u >> 16);
}

// ================= CSR build (bucketed, write-local) =================
#define EPB 4096   // edges per block in P1/P2

__global__ __launch_bounds__(256) void bucket_hist(const int* __restrict__ dst,
                                                   int* __restrict__ gcnt,
                                                   int* __restrict__ relBase,
                                                   int E, int N, int NB) {
    __shared__ int hist[256];
    int t = threadIdx.x, blk = blockIdx.x;
    if (t < NB) hist[t] = 0;
    __syncthreads();
    int e0 = blk * EPB + t;
#pragma unroll 4
    for (int k = 0; k < EPB / 256; ++k) {
        int e = e0 + k * 256;
        if (e < E) {
            int d = dst[e];
            if ((unsigned)d < (unsigned)N) atomicAdd(&hist[d >> 9], 1);
        }
    }
    __syncthreads();
    if (t < NB) relBase[blk * NB + t] = atomicAdd(&gcnt[t], hist[t]);
}

__global__ __launch_bounds__(256) void scan_buckets(const int* __restrict__ gcnt,
                                                    int* __restrict__ gboff, int NB) {
    __shared__ int sm[256];
    int t = threadIdx.x;
    int v = (t < NB) ? gcnt[t] : 0;
    sm[t] = v;
    __syncthreads();
#pragma unroll
    for (int o = 1; o < 256; o <<= 1) {
        int u = (t >= o) ? sm[t - o] : 0;
        __syncthreads();
        sm[t] += u;
        __syncthreads();
    }
    if (t < NB) gboff[t] = sm[t] - v;
    if (t == NB - 1) gboff[NB] = sm[t];
}

// P2: scatter packed (src | dlow<<23) into bucket-contiguous order.
// Valid for N < 2^23 (src fits 23 bits); dlow = d & 511 (9 bits).
__global__ __launch_bounds__(256) void bucket_scatter(const int* __restrict__ src,
                                                      const int* __restrict__ dst,
                                                      const int* __restrict__ gboff,
                                                      const int* __restrict__ relBase,
                                                      int* __restrict__ eb,
                                                      int E, int N, int NB) {
    __shared__ int cur[256];
    int t = threadIdx.x, blk = blockIdx.x;
    if (t < NB) cur[t] = gboff[t] + relBase[blk * NB + t];
    __syncthreads();
    int e0 = blk * EPB + t;
#pragma unroll 4
    for (int k = 0; k < EPB / 256; ++k) {
        int e = e0 + k * 256;
        if (e < E) {
            int d = dst[e];
            if ((unsigned)d < (unsigned)N) {
                int pos = atomicAdd(&cur[d >> 9], 1);
                eb[pos] = src[e] | ((d & 511) << 23);
            }
        }
    }
}

// P3: one 512-thread block per bucket; local count + LDS scan -> offs,
// then csr writes confined to a ~32KB window.
__global__ __launch_bounds__(512) void csr_build(const int* __restrict__ eb,
                                                 const int* __restrict__ gboff,
                                                 int* __restrict__ offs,
                                                 int* __restrict__ csr,
                                                 int N, int NB) {
    __shared__ int lcnt[512];
    __shared__ int sm[512];
    __shared__ int cur[512];
    int t = threadIdx.x, b = blockIdx.x;
    lcnt[t] = 0;
    __syncthreads();
    int s0 = gboff[b], s1 = gboff[b + 1];
    for (int e = s0 + t; e < s1; e += 512) atomicAdd(&lcnt[(unsigned)eb[e] >> 23], 1);
    __syncthreads();
    int v = lcnt[t];
    sm[t] = v;
    __syncthreads();
#pragma unroll
    for (int o = 1; o < 512; o <<= 1) {
        int u = (t >= o) ? sm[t - o] : 0;
        __syncthreads();
        sm[t] += u;
        __syncthreads();
    }
    int base = gboff[b] + sm[t] - v;
    cur[t] = base;
    int n0 = (b << 9) + t;
    if (n0 < N) offs[n0] = base;
    if (b == NB - 1 && t == 0) offs[N] = gboff[NB];
    __syncthreads();
    for (int e = s0 + t; e < s1; e += 512) {
        int p = eb[e];
        int pos = atomicAdd(&cur[(unsigned)p >> 23], 1);
        csr[pos] = p & 0x7FFFFF;
    }
}

// ================= W pre-transpose to bf16: WT[n][k] =================

__global__ __launch_bounds__(256) void prep_wT(const float* __restrict__ W1,
                                               const float* __restrict__ W2,
                                               const float* __restrict__ Wr,
                                               unsigned short* __restrict__ T1,
                                               unsigned short* __restrict__ T2,
                                               unsigned short* __restrict__ Tr) {
    int b = blockIdx.x, t = threadIdx.x;
    const float* W = b == 0 ? W1 : b == 1 ? W2 : Wr;
    unsigned short* O = b == 0 ? T1 : b == 1 ? T2 : Tr;
#pragma unroll 4
    for (int i = 0; i < 64; ++i) {
        int idx = t + 256 * i;
        int k = idx >> 7, n = idx & 127;
        O[n * 128 + k] = f2bf(W[k * 128 + n]);
    }
}

// ================= MFMA GEMM: OUT[N,128] = X[N,128] @ W[128,128] =================
// X fp32 -> bf16 staged in LDS (padded pitch 136 -> 2-way bank aliasing, free).
// WT bf16 [n][k] staged padded. mfma_f32_16x16x32_bf16:
//   A[m=lane&15][k=quad*8+j], B[k=quad*8+j][n=lane&15], D: col=lane&15,row=quad*4+reg.
// Block = 64 rows x 128 cols, 4 waves (16 rows each), K=128 in 4 steps.
#define WP 136

__global__ __launch_bounds__(256) void gemm_mfma(const float* __restrict__ X,
                                                 const unsigned short* __restrict__ WT,
                                                 float* __restrict__ OUT,
                                                 unsigned short* __restrict__ HB,
                                                 const float* __restrict__ bias,
                                                 int accumulate, int N) {
    __shared__ unsigned short Xs[64 * WP];
    __shared__ unsigned short Ws[128 * WP];
    int t = threadIdx.x;
    int row0 = blockIdx.x << 6;
    // stage X: 64x128 fp32 -> bf16 (rows >= N zero-padded)
#pragma unroll
    for (int i = 0; i < 8; ++i) {
        int f = t + 256 * i;           // float4 index; 32 per row
        int r = f >> 5, c4 = f & 31;
        float4 v = make_float4(0.f, 0.f, 0.f, 0.f);
        if (row0 + r < N) v = *(const float4*)(X + (size_t)(row0 + r) * 128 + c4 * 4);
        ushort4 u;
        u.x = f2bf(v.x); u.y = f2bf(v.y); u.z = f2bf(v.z); u.w = f2bf(v.w);
        *(ushort4*)&Xs[r * WP + c4 * 4] = u;
    }
    // stage WT: 128x128 bf16 (16B chunks)
#pragma unroll
    for (int i = 0; i < 8; ++i) {
        int f = t + 256 * i;           // ushort8 chunk; 16 per row
        int r = f >> 4, c8 = f & 15;
        *(uint4*)&Ws[r * WP + c8 * 8] = *(const uint4*)(WT + r * 128 + c8 * 8);
    }
    __syncthreads();

    int lane = t & 63;
    int wv = t >> 6;
    int col = lane & 15, quad = lane >> 4;
    f32x4 acc[8];
#pragma unroll
    for (int ct = 0; ct < 8; ++ct) acc[ct] = (f32x4){0.f, 0.f, 0.f, 0.f};
#pragma unroll
    for (int k0 = 0; k0 < 128; k0 += 32) {
        bf16x8 a = *(const bf16x8*)&Xs[(wv * 16 + col) * WP + k0 + quad * 8];
#pragma unroll
        for (int ct = 0; ct < 8; ++ct) {
            bf16x8 b = *(const bf16x8*)&Ws[(ct * 16 + col) * WP + k0 + quad * 8];
            acc[ct] = __builtin_amdgcn_mfma_f32_16x16x32_bf16(a, b, acc[ct], 0, 0, 0);
        }
    }
#pragma unroll
    for (int ct = 0; ct < 8; ++ct) {
        int c = ct * 16 + col;
        float bv = bias ? bias[c] : 0.f;
#pragma unroll
        for (int reg = 0; reg < 4; ++reg) {
            int grow = row0 + wv * 16 + quad * 4 + reg;
            if (grow < N) {
                float o = acc[ct][reg] + bv;
                if (OUT) {
                    if (accumulate) o += OUT[(size_t)grow * 128 + c];
                    OUT[(size_t)grow * 128 + c] = o;
                }
                if (HB) HB[(size_t)grow * 128 + c] = f2bf(o);
            }
        }
    }
}

// ============ attention scores per node from bf16 h (SoA by head) ============

__global__ __launch_bounds__(256) void s_kernel_bf(const unsigned short* __restrict__ hb,
                                                   const float* __restrict__ a_s,
                                                   const float* __restrict__ a_d,
                                                   float* __restrict__ sSt,
                                                   float* __restrict__ sDt, int N) {
    int gid = blockIdx.x * 256 + threadIdx.x;
    if (gid >= N * 4) return;
    int n = gid >> 2, hd = gid & 3;
    const uint4* hp = (const uint4*)(hb + (size_t)n * 128 + hd * 32);
    const float* as = a_s + hd * 32;
    const float* ad = a_d + hd * 32;
    float ss = 0.f, sd = 0.f;
#pragma unroll
    for (int q = 0; q < 4; ++q) {
        uint4 v = hp[q];
        unsigned vv[4] = {v.x, v.y, v.z, v.w};
#pragma unroll
        for (int j = 0; j < 4; ++j) {
            float lo = __uint_as_float(vv[j] << 16);
            float hi = __uint_as_float(vv[j] & 0xffff0000u);
            int c = q * 8 + 2 * j;
            ss = fmaf(lo, as[c], ss);
            sd = fmaf(lo, ad[c], sd);
            ss = fmaf(hi, as[c + 1], ss);
            sd = fmaf(hi, ad[c + 1], sd);
        }
    }
    sSt[(size_t)hd * N + n] = ss;
    sDt[(size_t)hd * N + n] = sd;
}

// ============ fused softmax-weight + gather-accumulate (v5) ============

__global__ __launch_bounds__(256) void agg5_kernel(const unsigned short* __restrict__ hb,
                                                   const float* __restrict__ sSt,
                                                   const float* __restrict__ sDt,
                                                   const int* __restrict__ offs,
                                                   const int* __restrict__ csr,
                                                   const float* __restrict__ bias,
                                                   float* __restrict__ out,
                                                   int do_relu, int N) {
    int n = (blockIdx.x << 2) + (threadIdx.x >> 6);
    if (n >= N) return;
    int lane = threadIdx.x & 63;
    int half = lane >> 5;
    int cl = lane & 31;
    int hd = cl >> 3;
    int whead = lane >> 4;
    int sub = lane & 15;

    size_t wb = (size_t)whead * N;
    float sdh = sDt[wb + n];
    float selfw = __expf(leaky1(sSt[wb + n] + sdh));

    float4 acc = make_float4(0.f, 0.f, 0.f, 0.f);
    float wsum = 0.f;

    int off = offs[n], end = offs[n + 1];
    for (int base = off; base < end; base += 64) {
        int idx = base + lane;
        int spre = (idx < end) ? csr[idx] : 0;
        int cnt = min(64, end - base);
#pragma unroll 1
        for (int lo = 0; lo < cnt; lo += 16) {
            float w = 0.f;
            {
                int s2 = __shfl(spre, lo + sub);
                if (lo + sub < cnt) w = __expf(leaky1(sSt[wb + s2] + sdh));
            }
            wsum += w;
#pragma unroll
            for (int i = 0; i < 16; i += 2) {
                int sj = __shfl(spre, lo + i + half);
                float wj = __shfl(w, (hd << 4) + i + half);
                uint2 v = *(const uint2*)(hb + (size_t)sj * 128 + 4 * cl);
                acc.x = fmaf(wj, __uint_as_float(v.x << 16), acc.x);
                acc.y = fmaf(wj, __uint_as_float(v.x & 0xffff0000u), acc.y);
                acc.z = fmaf(wj, __uint_as_float(v.y << 16), acc.z);
                acc.w = fmaf(wj, __uint_as_float(v.y & 0xffff0000u), acc.w);
            }
        }
    }
    acc.x += __shfl_xor(acc.x, 32);
    acc.y += __shfl_xor(acc.y, 32);
    acc.z += __shfl_xor(acc.z, 32);
    acc.w += __shfl_xor(acc.w, 32);
#pragma unroll
    for (int o = 8; o > 0; o >>= 1) wsum += __shfl_xor(wsum, o);
    float denom = wsum + selfw;
    float iv = 1.0f / __shfl(denom, hd << 4);
    float sw = __shfl(selfw, hd << 4);

    if (half == 0) {
        uint2 hv = *(const uint2*)(hb + (size_t)n * 128 + 4 * cl);
        float4 hs;
        hs.x = __uint_as_float(hv.x << 16);
        hs.y = __uint_as_float(hv.x & 0xffff0000u);
        hs.z = __uint_as_float(hv.y << 16);
        hs.w = __uint_as_float(hv.y & 0xffff0000u);
        float4 bvv = *(const float4*)(bias + 4 * cl);
        float4 o;
        o.x = fmaf(fmaf(sw, hs.x, acc.x), iv, bvv.x);
        o.y = fmaf(fmaf(sw, hs.y, acc.y), iv, bvv.y);
        o.z = fmaf(fmaf(sw, hs.z, acc.z), iv, bvv.z);
        o.w = fmaf(fmaf(sw, hs.w, acc.w), iv, bvv.w);
        if (do_relu) {
            o.x = fmaxf(o.x, 0.f); o.y = fmaxf(o.y, 0.f);
            o.z = fmaxf(o.z, 0.f); o.w = fmaxf(o.w, 0.f);
        }
        *(float4*)(out + (size_t)n * 128 + 4 * cl) = o;
    }
}

// ================= host =================

extern "C" void kernel_launch(void* const* d_in, const int* in_sizes, int n_in,
                              void* d_out, int out_size, void* d_ws, size_t ws_size,
                              hipStream_t stream) {
    const float* x   = (const float*)d_in[0];
    const int*   ei  = (const int*)d_in[1];
    const float* W1  = (const float*)d_in[2];
    const float* a1s = (const float*)d_in[3];
    const float* a1d = (const float*)d_in[4];
    const float* b1  = (const float*)d_in[5];
    const float* W2  = (const float*)d_in[6];
    const float* a2s = (const float*)d_in[7];
    const float* a2d = (const float*)d_in[8];
    const float* b2  = (const float*)d_in[9];
    const float* Wr  = (const float*)d_in[10];
    const float* br  = (const float*)d_in[11];
    float* out = (float*)d_out;

    int N = in_sizes[0] / 128;
    int E = in_sizes[1] / 2;
    const int* src = ei;
    const int* dst = ei + E;
    int NB = (N + 511) >> 9;
    int ebl = (E + EPB - 1) / EPB;

    char* w = (char*)d_ws;
    size_t p = 0;
    auto take = [&](size_t bytes) -> char* {
        char* r = w + p;
        p = (p + bytes + 255) & ~(size_t)255;
        return r;
    };
    float* bufB = (float*)take((size_t)N * 128 * 4);                  // h1 fp32
    unsigned short* hb = (unsigned short*)take((size_t)N * 128 * 2);  // h bf16
    unsigned short* wT1 = (unsigned short*)take(128 * 128 * 2);
    unsigned short* wT2 = (unsigned short*)take(128 * 128 * 2);
    unsigned short* wTr = (unsigned short*)take(128 * 128 * 2);
    float* sSt  = (float*)take((size_t)N * 4 * 4);
    float* sDt  = (float*)take((size_t)N * 4 * 4);
    int* gcnt   = (int*)take((size_t)256 * 4);
    int* offs   = (int*)take((size_t)(N + 1) * 4);
    int* gboff  = (int*)take((size_t)257 * 4);
    int* relBase = (int*)take((size_t)ebl * NB * 4);
    int* eb     = (int*)take((size_t)E * 4);
    int* csr    = (int*)take((size_t)E * 4);

    hipMemsetAsync(gcnt, 0, 256 * 4, stream);

    prep_wT<<<3, 256, 0, stream>>>(W1, W2, Wr, wT1, wT2, wTr);
    bucket_hist<<<ebl, 256, 0, stream>>>(dst, gcnt, relBase, E, N, NB);
    scan_buckets<<<1, 256, 0, stream>>>(gcnt, gboff, NB);
    bucket_scatter<<<ebl, 256, 0, stream>>>(src, dst, gboff, relBase, eb, E, N, NB);
    csr_build<<<NB, 512, 0, stream>>>(eb, gboff, offs, csr, N, NB);

    int gb = (N + 63) / 64;
    int sb = (N * 4 + 255) / 256;
    int ab = (N + 3) / 4;

    // layer 1: MFMA gemm emits bf16 h only; scores from hb
    gemm_mfma<<<gb, 256, 0, stream>>>(x, wT1, nullptr, hb, nullptr, 0, N);
    s_kernel_bf<<<sb, 256, 0, stream>>>(hb, a1s, a1d, sSt, sDt, N);
    agg5_kernel<<<ab, 256, 0, stream>>>(hb, sSt, sDt, offs, csr, b1, bufB, 1, N);
    // layer 2
    gemm_mfma<<<gb, 256, 0, stream>>>(bufB, wT2, nullptr, hb, nullptr, 0, N);
    s_kernel_bf<<<sb, 256, 0, stream>>>(hb, a2s, a2d, sSt, sDt, N);
    agg5_kernel<<<ab, 256, 0, stream>>>(hb, sSt, sDt, offs, csr, b2, out, 0, N);
    // residual: out += x @ Wr + br
    gemm_mfma<<<gb, 256, 0, stream>>>(x, wTr, out, nullptr, br, 1, N);
}